// Round 3
// baseline (682.746 us; speedup 1.0000x reference)
//
#include <hip/hip_runtime.h>
#include <hip/hip_bf16.h>

#define NV 1000000
#define CI 32
#define CO 64
#define KK 9
#define NG (NV / 16)          // 62500 voxel-groups of 16 (exact)
#define EPSV 1e-5f

typedef __bf16 bf16x8 __attribute__((ext_vector_type(8)));
typedef float  f32x4  __attribute__((ext_vector_type(4)));

__device__ __forceinline__ f32x4 mfma16(bf16x8 a, bf16x8 b, f32x4 c) {
    // D[16x16] = A[16x32] * B[32x16] + C
    // A: row=lane&15, k=(lane>>4)*8+j ; B: col=lane&15, k=(lane>>4)*8+j
    // D: col=lane&15, row=(lane>>4)*4+reg   [learn_hip m89 verified]
    return __builtin_amdgcn_mfma_f32_16x16x32_bf16(a, b, c, 0, 0, 0);
}

__device__ __forceinline__ float xredseg(float v) {
    v += __shfl_xor(v, 16, 64);
    v += __shfl_xor(v, 32, 64);
    return v;
}

// ---------------- prep: transpose weights to [k][co][ci] bf16 ----------------
__global__ void k_prep_w(const float* __restrict__ W1, const float* __restrict__ W2,
                         const float* __restrict__ Wd,
                         __bf16* __restrict__ W1T, __bf16* __restrict__ W2T,
                         __bf16* __restrict__ WdT) {
    int i = blockIdx.x * blockDim.x + threadIdx.x;
    const int n1 = KK * CO * CI;      // 18432
    const int n2 = KK * CO * CO;      // 36864
    const int nd = CO * CI;           // 2048
    if (i < n1) {
        int k = i / (CO * CI), r = i % (CO * CI), co = r / CI, ci = r % CI;
        W1T[i] = (__bf16)W1[(k * CI + ci) * CO + co];
    } else if (i < n1 + n2) {
        int j = i - n1;
        int k = j / (CO * CO), r = j % (CO * CO), co = r / CO, ci = r % CO;
        W2T[j] = (__bf16)W2[(k * CO + ci) * CO + co];
    } else if (i < n1 + n2 + nd) {
        int j = i - n1 - n2;
        int co = j / CI, ci = j % CI;
        WdT[j] = (__bf16)Wd[ci * CO + co];
    }
}

// ---------------- prep: x fp32 -> bf16 ----------------
__global__ void k_prep_x(const float* __restrict__ x, __bf16* __restrict__ xb) {
    int i = blockIdx.x * blockDim.x + threadIdx.x;   // one thread per 8 elems
    const float4* px = (const float4*)x + 2 * (size_t)i;
    float4 u = px[0], v = px[1];
    bf16x8 o;
    o[0] = (__bf16)u.x; o[1] = (__bf16)u.y; o[2] = (__bf16)u.z; o[3] = (__bf16)u.w;
    o[4] = (__bf16)v.x; o[5] = (__bf16)v.y; o[6] = (__bf16)v.z; o[7] = (__bf16)v.w;
    *((bf16x8*)xb + i) = o;
}

// ---------------- conv1: per-wave LDS-pipelined gather-MFMA + dense stats ----------------
// Each wave owns a private double-buffered LDS tile (2 x 9216 B): tile = one gid's
// 16 voxels x 9 neighbor rows x 64 B, layout [k][voxel][16B-part]. Staging is
// 9 x global_load_lds (wave-uniform LDS base + lane*16; lane -> voxel=lane>>2,
// part=lane&3 so 4 consecutive lanes cover one 64-B row = coalesced request).
// Pipeline: issue tile n+1's gathers + tile n+2's idx loads (volatile -> exactly
// 9 vmcnt ops), then counted s_waitcnt vmcnt(18) drains ONLY tile n's gathers.
// No __syncthreads anywhere: waves are independent -> gathers in flight ~100%.
__global__ __launch_bounds__(256, 2) void k_conv1(
    const __bf16* __restrict__ xb, const int* __restrict__ nbr,
    const __bf16* __restrict__ W1T, const __bf16* __restrict__ WdT,
    __bf16* __restrict__ y1b, float* __restrict__ stats) {
    __shared__ __align__(16) char smem[4][2][KK * 1024];   // 73728 B -> 2 blocks/CU

    const int lane = threadIdx.x & 63;
    const int w    = threadIdx.x >> 6;
    const int r    = lane & 15;
    const int seg  = lane >> 4;
    const int rq   = lane >> 2;        // staging voxel row 0..15
    const int part = lane & 3;         // staging 16-B part of the 64-B row

    bf16x8 w1[KK][4];
#pragma unroll
    for (int k = 0; k < KK; k++)
#pragma unroll
        for (int t = 0; t < 4; t++)
            w1[k][t] = *(const bf16x8*)(W1T + ((size_t)(k * CO + t * 16 + r)) * CI + seg * 8);
    bf16x8 wd[4];
#pragma unroll
    for (int t = 0; t < 4; t++)
        wd[t] = *(const bf16x8*)(WdT + (size_t)(t * 16 + r) * CI + seg * 8);

    float ps1[4] = {0.f,0.f,0.f,0.f}, pq1[4] = {0.f,0.f,0.f,0.f};
    float psd[4] = {0.f,0.f,0.f,0.f}, pqd[4] = {0.f,0.f,0.f,0.f};

    const int slot   = blockIdx.x * 4 + w;
    const int stride = gridDim.x * 4;
    const f32x4 z = {0.f, 0.f, 0.f, 0.f};

    int idxs[KK];
    // volatile -> exactly 9 separate global_load_dword (no merging) so the
    // counted vmcnt below is static
    auto load_idx = [&](int it) {
        const volatile int* nb = nbr + (size_t)it * (16 * KK) + rq * KK;
#pragma unroll
        for (int k = 0; k < KK; k++) idxs[k] = nb[k];
    };
    auto stage = [&](int buf) {
        char* dst = smem[w][buf];
#pragma unroll
        for (int k = 0; k < KK; k++) {
            const __bf16* src = xb + (size_t)idxs[k] * CI + part * 8;
            __builtin_amdgcn_global_load_lds(
                (const __attribute__((address_space(1))) void*)src,
                (__attribute__((address_space(3))) void*)(dst + k * 1024),
                16, 0, 0);
        }
    };

    int it  = slot;                // slot < 2048 < NG always
    load_idx(it);
    stage(0);                      // gathers(it): auto-waits on idxs (once)
    int nxt = it + stride;
    if (nxt < NG) load_idx(nxt);
    int cur = 0;

    while (true) {
        const int nxt2 = nxt + stride;
        if (nxt < NG) {
            stage(cur ^ 1);                 // gathers(nxt) fly during compute(it)
            if (nxt2 < NG) load_idx(nxt2);  // idx for the tile after that
        }
        __builtin_amdgcn_sched_barrier(0);
        if (nxt2 < NG)      asm volatile("s_waitcnt vmcnt(18)" ::: "memory");
        else if (nxt < NG)  asm volatile("s_waitcnt vmcnt(9)"  ::: "memory");
        else                asm volatile("s_waitcnt vmcnt(0)"  ::: "memory");
        __builtin_amdgcn_sched_barrier(0);

        // ---- compute tile `it` from smem[w][cur] ----
        const __bf16* base = (const __bf16*)smem[w][cur];
        const int vb = it * 16;

        f32x4 acc[4]  = {z, z, z, z};
        f32x4 accd[4] = {z, z, z, z};

        bf16x8 ad = *(const bf16x8*)(xb + (size_t)(vb + r) * CI + seg * 8);
#pragma unroll
        for (int t = 0; t < 4; t++) accd[t] = mfma16(ad, wd[t], accd[t]);

#pragma unroll
        for (int k = 0; k < KK; k++) {
            bf16x8 a = *(const bf16x8*)(base + k * 512 + r * 32 + seg * 8);
#pragma unroll
            for (int t = 0; t < 4; t++) acc[t] = mfma16(a, w1[k][t], acc[t]);
        }

#pragma unroll
        for (int t = 0; t < 4; t++) {
#pragma unroll
            for (int rr = 0; rr < 4; rr++) {
                float val = acc[t][rr];
                int row = vb + seg * 4 + rr;
                __builtin_nontemporal_store((__bf16)val, &y1b[(size_t)row * CO + t * 16 + r]);
                ps1[t] += val; pq1[t] += val * val;
                float dv = accd[t][rr];
                psd[t] += dv; pqd[t] += dv * dv;
            }
        }

        if (nxt >= NG) break;
        it = nxt; nxt = nxt2; cur ^= 1;
    }

#pragma unroll
    for (int t = 0; t < 4; t++) {
        ps1[t] = xredseg(ps1[t]); pq1[t] = xredseg(pq1[t]);
        psd[t] = xredseg(psd[t]); pqd[t] = xredseg(pqd[t]);
    }
    if (lane < 16) {
#pragma unroll
        for (int t = 0; t < 4; t++) {
            atomicAdd(&stats[0 * 64 + t * 16 + lane], ps1[t]);
            atomicAdd(&stats[1 * 64 + t * 16 + lane], pq1[t]);
            atomicAdd(&stats[2 * 64 + t * 16 + lane], psd[t]);
            atomicAdd(&stats[3 * 64 + t * 16 + lane], pqd[t]);
        }
    }
}

// ---------------- BN + ReLU, in place on y1b (bf16) ----------------
__global__ void k_bnrelu(__bf16* __restrict__ y1b, const float* __restrict__ stats,
                         const float* __restrict__ g1, const float* __restrict__ b1) {
    __shared__ float sc[CO], sh[CO];
    int t = threadIdx.x;
    if (t < CO) {
        float mu  = stats[0 * 64 + t] * (1.0f / NV);
        float var = stats[1 * 64 + t] * (1.0f / NV) - mu * mu;
        float s = g1[t] * rsqrtf(var + EPSV);
        sc[t] = s; sh[t] = b1[t] - mu * s;
    }
    __syncthreads();
    size_t i = (size_t)blockIdx.x * blockDim.x + threadIdx.x;   // one per 8 elems
    bf16x8* p = (bf16x8*)y1b + i;
    bf16x8 vv = *p;
    int c0 = 8 * ((int)(i & 7));
    bf16x8 o;
#pragma unroll
    for (int j = 0; j < 8; j++) {
        float f = (float)vv[j];
        f = sc[c0 + j] * f + sh[c0 + j];
        o[j] = (__bf16)fmaxf(f, 0.f);
    }
    *p = o;
}

// ---------------- conv2: LDS-staged gather-MFMA on h1 + stats2 ----------------
// 128-thread blocks. Per iteration (one gid = 16 voxels), both waves share ONE
// staged tile of 16x9 rows x 128B = 18KB (gather traffic halved vs per-wave
// gathers). Staging via global_load_lds: 8 consecutive lanes cover one 128B row
// -> full-line coalesced requests. XOR part-swizzle (p ^= i&7), pre-applied on
// the GLOBAL source address (LDS dest must stay linear), makes the ds_read_b128
// consumption spread 8 dwords/bank (optimal).
#define TILE_B (16 * KK * 128)     // 18432 B per buffer

__global__ __launch_bounds__(128, 2) void k_conv2(
    const __bf16* __restrict__ h1b, const int* __restrict__ nbr,
    const __bf16* __restrict__ W2T,
    float* __restrict__ y2, float* __restrict__ stats) {
    __shared__ __align__(16) char smem[2][TILE_B];   // 36864 B -> 4 blocks/CU

    const int lane = threadIdx.x & 63;
    const int w    = threadIdx.x >> 6;      // 0..1 = co-half (thalf)
    const int r    = lane & 15;
    const int seg  = lane >> 4;

    bf16x8 w2[KK][2][2];                    // [k][t2][s]
#pragma unroll
    for (int k = 0; k < KK; k++)
#pragma unroll
        for (int t2 = 0; t2 < 2; t2++)
#pragma unroll
            for (int s = 0; s < 2; s++) {
                int co = w * 32 + t2 * 16 + r;
                int ci = s * 32 + seg * 8;
                w2[k][t2][s] = *(const bf16x8*)(W2T + ((size_t)(k * CO + co)) * CO + ci);
            }

    float ps[2] = {0.f, 0.f}, pq[2] = {0.f, 0.f};
    const f32x4 z = {0.f, 0.f, 0.f, 0.f};
    const int sw = r & 7;

    // ---- staging: wave w stages chunks c = w*576 + s*64 + lane of this gid's
    // 1152 16B-chunks. c -> (ruleIdx = c>>3 in [0,144), part p_lin = c&7);
    // i = ruleIdx/9 (magic div, valid for ruleIdx<512); global source part is
    // swizzled: p = p_lin ^ (i&7).
    auto stage = [&](char* buf, int it) {
        const int* nb = nbr + (size_t)it * (16 * KK);
#pragma unroll
        for (int s = 0; s < 9; s++) {
            int c = w * 576 + s * 64 + lane;
            int ruleIdx = c >> 3;
            int i = (ruleIdx * 57) >> 9;          // floor(ruleIdx/9), ruleIdx<512
            int p = (c & 7) ^ (i & 7);
            int idx = nb[ruleIdx];
            const __bf16* src = h1b + (size_t)idx * CO + p * 8;
            __builtin_amdgcn_global_load_lds(
                (const __attribute__((address_space(1))) void*)src,
                (__attribute__((address_space(3))) void*)(buf + w * 9216 + s * 1024),
                16, 0, 0);
        }
    };

    int it = blockIdx.x;
    int cur = 0;
    if (it < NG) stage(smem[0], it);
    __syncthreads();                         // drains vmcnt(0) before barrier

    for (; it < NG; it += gridDim.x) {
        int nxt = it + gridDim.x;
        if (nxt < NG) stage(smem[cur ^ 1], nxt);   // prefetch overlaps compute

        // ---- compute on staged tile ----
        const __bf16* base = (const __bf16*)smem[cur];
        f32x4 acc[2] = {z, z};
#pragma unroll
        for (int k = 0; k < KK; k++) {
            const __bf16* rp = base + (size_t)(r * KK + k) * 64;
            bf16x8 a0 = *(const bf16x8*)(rp + ((seg ^ sw) * 8));
            bf16x8 a1 = *(const bf16x8*)(rp + (((4 + seg) ^ sw) * 8));
            acc[0] = mfma16(a0, w2[k][0][0], acc[0]);
            acc[0] = mfma16(a1, w2[k][0][1], acc[0]);
            acc[1] = mfma16(a0, w2[k][1][0], acc[1]);
            acc[1] = mfma16(a1, w2[k][1][1], acc[1]);
        }

        const int vb = it * 16;
#pragma unroll
        for (int t2 = 0; t2 < 2; t2++) {
#pragma unroll
            for (int rr = 0; rr < 4; rr++) {
                float val = acc[t2][rr];
                int row = vb + seg * 4 + rr;
                int c = w * 32 + t2 * 16 + r;
                // non-temporal: y2 write stream must not evict h1b from L3
                __builtin_nontemporal_store(val, &y2[(size_t)row * CO + c]);
                ps[t2] += val; pq[t2] += val * val;
            }
        }

        __syncthreads();                     // drains staging vmcnt + barrier
        cur ^= 1;
    }

#pragma unroll
    for (int t2 = 0; t2 < 2; t2++) { ps[t2] = xredseg(ps[t2]); pq[t2] = xredseg(pq[t2]); }
    if (lane < 16) {
#pragma unroll
        for (int t2 = 0; t2 < 2; t2++) {
            atomicAdd(&stats[4 * 64 + w * 32 + t2 * 16 + lane], ps[t2]);
            atomicAdd(&stats[5 * 64 + w * 32 + t2 * 16 + lane], pq[t2]);
        }
    }
}

// ---------------- final: out = relu(BN2(y2) + BNd(xb@WdT)), in place on d_out ----------------
__global__ __launch_bounds__(256, 2) void k_final(
    const __bf16* __restrict__ xb, const __bf16* __restrict__ WdT,
    float* __restrict__ out, const float* __restrict__ stats,
    const float* __restrict__ g2, const float* __restrict__ b2,
    const float* __restrict__ gd, const float* __restrict__ bd) {
    __shared__ float s2[CO], sh2[CO], sdv[CO], shd[CO];
    int t = threadIdx.x;
    if (t < CO) {
        float mu2  = stats[4 * 64 + t] * (1.0f / NV);
        float var2 = stats[5 * 64 + t] * (1.0f / NV) - mu2 * mu2;
        float s = g2[t] * rsqrtf(var2 + EPSV);
        s2[t] = s; sh2[t] = b2[t] - mu2 * s;
        float mud  = stats[2 * 64 + t] * (1.0f / NV);
        float vard = stats[3 * 64 + t] * (1.0f / NV) - mud * mud;
        float sd = gd[t] * rsqrtf(vard + EPSV);
        sdv[t] = sd; shd[t] = bd[t] - mud * sd;
    }
    __syncthreads();

    const int lane = threadIdx.x & 63;
    const int w    = threadIdx.x >> 6;
    const int r    = lane & 15;
    const int seg  = lane >> 4;

    bf16x8 wd[4];
#pragma unroll
    for (int t4 = 0; t4 < 4; t4++)
        wd[t4] = *(const bf16x8*)(WdT + (size_t)(t4 * 16 + r) * CI + seg * 8);

    const int slot = blockIdx.x * 4 + w;
    const int nslots = gridDim.x * 4;
    const f32x4 z = {0.f, 0.f, 0.f, 0.f};

    for (int gid = slot; gid < NG; gid += nslots) {
        const int vb = gid * 16;
        const int v  = vb + r;
        bf16x8 ad = *(const bf16x8*)(xb + (size_t)v * CI + seg * 8);
        f32x4 accd[4] = {z, z, z, z};
#pragma unroll
        for (int t4 = 0; t4 < 4; t4++) accd[t4] = mfma16(ad, wd[t4], accd[t4]);
#pragma unroll
        for (int t4 = 0; t4 < 4; t4++) {
#pragma unroll
            for (int rr = 0; rr < 4; rr++) {
                int row = vb + seg * 4 + rr;
                int c = t4 * 16 + r;
                size_t o = (size_t)row * CO + c;
                float y2v = out[o];
                float res = s2[c] * y2v + sh2[c] + sdv[c] * accd[t4][rr] + shd[c];
                out[o] = fmaxf(res, 0.f);
            }
        }
    }
}

extern "C" void kernel_launch(void* const* d_in, const int* in_sizes, int n_in,
                              void* d_out, int out_size, void* d_ws, size_t ws_size,
                              hipStream_t stream) {
    const float* x  = (const float*)d_in[0];
    const float* W1 = (const float*)d_in[1];
    const float* g1 = (const float*)d_in[2];
    const float* b1 = (const float*)d_in[3];
    const float* W2 = (const float*)d_in[4];
    const float* g2 = (const float*)d_in[5];
    const float* b2 = (const float*)d_in[6];
    const float* Wd = (const float*)d_in[7];
    const float* gd = (const float*)d_in[8];
    const float* bd = (const float*)d_in[9];
    const int*  nbr = (const int*)d_in[10];

    char* ws = (char*)d_ws;
    __bf16* xb  = (__bf16*)ws;                              // 64,000,000 B
    __bf16* y1b = (__bf16*)(ws + 64000000);                 // 128,000,000 B
    __bf16* W1T = (__bf16*)(ws + 192000000);                // 36,864 B
    __bf16* W2T = W1T + KK * CO * CI;                       // 73,728 B
    __bf16* WdT = W2T + KK * CO * CO;                       // 4,096 B
    float* stats = (float*)(ws + 192000000 + 2 * (KK*CO*CI + KK*CO*CO + CO*CI));

    hipMemsetAsync(stats, 0, 6 * 64 * sizeof(float), stream);

    int nprep = KK*CO*CI + KK*CO*CO + CO*CI;                // 57344
    k_prep_w<<<(nprep + 255) / 256, 256, 0, stream>>>(W1, W2, Wd, W1T, W2T, WdT);
    k_prep_x<<<(NV * CI / 8) / 256, 256, 0, stream>>>(x, xb);   // 15625 blocks
    k_conv1<<<512, 256, 0, stream>>>(xb, nbr, W1T, WdT, y1b, stats);
    k_bnrelu<<<(NV * CO / 8) / 256, 256, 0, stream>>>(y1b, stats, g1, b1);  // 31250 blocks
    k_conv2<<<1024, 128, 0, stream>>>(y1b, nbr, W2T, (float*)d_out, stats);
    k_final<<<1024, 256, 0, stream>>>(xb, WdT, (float*)d_out, stats, g2, b2, gd, bd);
}

// Round 4
// 601.805 us; speedup vs baseline: 1.1345x; 1.1345x over previous
//
#include <hip/hip_runtime.h>
#include <hip/hip_bf16.h>

#define NV 1000000
#define CI 32
#define CO 64
#define KK 9
#define NG (NV / 16)          // 62500 voxel-groups of 16 (exact)
#define EPSV 1e-5f

typedef __bf16 bf16x8 __attribute__((ext_vector_type(8)));
typedef float  f32x4  __attribute__((ext_vector_type(4)));

__device__ __forceinline__ f32x4 mfma16(bf16x8 a, bf16x8 b, f32x4 c) {
    // D[16x16] = A[16x32] * B[32x16] + C
    // A: row=lane&15, k=(lane>>4)*8+j ; B: col=lane&15, k=(lane>>4)*8+j
    // D: col=lane&15, row=(lane>>4)*4+reg   [learn_hip m89 verified]
    return __builtin_amdgcn_mfma_f32_16x16x32_bf16(a, b, c, 0, 0, 0);
}

__device__ __forceinline__ float xredseg(float v) {
    v += __shfl_xor(v, 16, 64);
    v += __shfl_xor(v, 32, 64);
    return v;
}

// ---------------- prep: transpose weights to [k][co][ci] bf16 ----------------
__global__ void k_prep_w(const float* __restrict__ W1, const float* __restrict__ W2,
                         const float* __restrict__ Wd,
                         __bf16* __restrict__ W1T, __bf16* __restrict__ W2T,
                         __bf16* __restrict__ WdT) {
    int i = blockIdx.x * blockDim.x + threadIdx.x;
    const int n1 = KK * CO * CI;      // 18432
    const int n2 = KK * CO * CO;      // 36864
    const int nd = CO * CI;           // 2048
    if (i < n1) {
        int k = i / (CO * CI), r = i % (CO * CI), co = r / CI, ci = r % CI;
        W1T[i] = (__bf16)W1[(k * CI + ci) * CO + co];
    } else if (i < n1 + n2) {
        int j = i - n1;
        int k = j / (CO * CO), r = j % (CO * CO), co = r / CO, ci = r % CO;
        W2T[j] = (__bf16)W2[(k * CO + ci) * CO + co];
    } else if (i < n1 + n2 + nd) {
        int j = i - n1 - n2;
        int co = j / CI, ci = j % CI;
        WdT[j] = (__bf16)Wd[ci * CO + co];
    }
}

// ---------------- prep: x fp32 -> bf16 ----------------
__global__ void k_prep_x(const float* __restrict__ x, __bf16* __restrict__ xb) {
    int i = blockIdx.x * blockDim.x + threadIdx.x;   // one thread per 8 elems
    const float4* px = (const float4*)x + 2 * (size_t)i;
    float4 u = px[0], v = px[1];
    bf16x8 o;
    o[0] = (__bf16)u.x; o[1] = (__bf16)u.y; o[2] = (__bf16)u.z; o[3] = (__bf16)u.w;
    o[4] = (__bf16)v.x; o[5] = (__bf16)v.y; o[6] = (__bf16)v.z; o[7] = (__bf16)v.w;
    *((bf16x8*)xb + i) = o;
}

// ---------------- conv1: register-double-buffered gather-MFMA, W1 in LDS ----------------
// MLP model: conv1 is outstanding-request limited. Per phase a wave keeps ~19 vm
// ops in flight (9 gathers + dense row + 9 next-next idx) while computing the
// previous tile from the OTHER register set; compiler emits counted per-register
// vmcnt waits (reliable for register loads). W1 lives in LDS (36 KB) to free
// ~144 VGPRs; a per-iteration asm launder on the LDS offset stops the compiler
// from hoisting the 36 fragment reads back into registers.
__global__ __launch_bounds__(256, 2) void k_conv1(
    const __bf16* __restrict__ xb, const int* __restrict__ nbr,
    const __bf16* __restrict__ W1T, const __bf16* __restrict__ WdT,
    __bf16* __restrict__ y1b, float* __restrict__ stats) {
    __shared__ __align__(16) char w1smem[KK * CO * CI * 2];   // 36864 B

    const int lane = threadIdx.x & 63;
    const int w    = threadIdx.x >> 6;
    const int r    = lane & 15;
    const int seg  = lane >> 4;

    // stage W1T -> LDS, linear copy: 2304 16B-chunks, 256 threads x 9
#pragma unroll
    for (int j = 0; j < 9; j++) {
        const __bf16* srcp = W1T + (size_t)(j * 256 + threadIdx.x) * 8;
        __builtin_amdgcn_global_load_lds(
            (const __attribute__((address_space(1))) void*)srcp,
            (__attribute__((address_space(3))) void*)(w1smem + j * 4096 + w * 1024),
            16, 0, 0);
    }
    __syncthreads();

    bf16x8 wd[4];
#pragma unroll
    for (int t = 0; t < 4; t++)
        wd[t] = *(const bf16x8*)(WdT + (size_t)(t * 16 + r) * CI + seg * 8);

    float ps1[4] = {0.f,0.f,0.f,0.f}, pq1[4] = {0.f,0.f,0.f,0.f};
    float psd[4] = {0.f,0.f,0.f,0.f}, pqd[4] = {0.f,0.f,0.f,0.f};

    const int slot   = blockIdx.x * 4 + w;
    const int stride = gridDim.x * 4;
    const f32x4 z = {0.f, 0.f, 0.f, 0.f};

    auto loadIdx = [&](int (&idx)[KK], int tile) {
        const int* nb = nbr + (size_t)(tile * 16 + r) * KK;
#pragma unroll
        for (int k = 0; k < KK; k++) idx[k] = nb[k];
    };
    auto gather9 = [&](bf16x8 (&g)[KK], const int (&idx)[KK]) {
#pragma unroll
        for (int k = 0; k < KK; k++)
            g[k] = *(const bf16x8*)(xb + (size_t)idx[k] * CI + seg * 8);
    };
    auto loadAd = [&](int tile) {
        return *(const bf16x8*)(xb + (size_t)(tile * 16 + r) * CI + seg * 8);
    };
    auto compute = [&](int tile, const bf16x8 (&g)[KK], bf16x8 ad) {
        int w1off = 0;
        asm volatile("" : "+v"(w1off));        // defeat cross-iteration hoisting
        const __bf16* wb = (const __bf16*)w1smem + w1off;

        f32x4 acc[4]  = {z, z, z, z};
        f32x4 accd[4] = {z, z, z, z};
#pragma unroll
        for (int t = 0; t < 4; t++) accd[t] = mfma16(ad, wd[t], accd[t]);
#pragma unroll
        for (int k = 0; k < KK; k++) {
#pragma unroll
            for (int t = 0; t < 4; t++) {
                bf16x8 b = *(const bf16x8*)(wb + k * 2048 + t * 512 + r * 32 + seg * 8);
                acc[t] = mfma16(g[k], b, acc[t]);
            }
        }

        const int vb = tile * 16;
#pragma unroll
        for (int t = 0; t < 4; t++) {
#pragma unroll
            for (int rr = 0; rr < 4; rr++) {
                float val = acc[t][rr];
                int row = vb + seg * 4 + rr;
                __builtin_nontemporal_store((__bf16)val, &y1b[(size_t)row * CO + t * 16 + r]);
                ps1[t] += val; pq1[t] += val * val;
                float dv = accd[t][rr];
                psd[t] += dv; pqd[t] += dv * dv;
            }
        }
    };

    int idx0[KK], idx1[KK];
    bf16x8 g0[KK], g1[KK];
    bf16x8 ad0, ad1;

    int it = slot;                    // slot < 3072 <= NG always
    loadIdx(idx0, it);
    gather9(g0, idx0); ad0 = loadAd(it);
    int itn = it + stride;
    bool have = (itn < NG);
    if (have) loadIdx(idx1, itn);

    while (true) {
        // phase A: compute(it, g0); prefetch tile itn into g1, idx for itn+stride
        if (have) {
            gather9(g1, idx1); ad1 = loadAd(itn);
            int it2 = itn + stride;
            if (it2 < NG) loadIdx(idx0, it2);
        }
        compute(it, g0, ad0);
        if (!have) break;
        it = itn; itn = it + stride; have = (itn < NG);

        // phase B: roles swapped
        if (have) {
            gather9(g0, idx0); ad0 = loadAd(itn);
            int it2 = itn + stride;
            if (it2 < NG) loadIdx(idx1, it2);
        }
        compute(it, g1, ad1);
        if (!have) break;
        it = itn; itn = it + stride; have = (itn < NG);
    }

#pragma unroll
    for (int t = 0; t < 4; t++) {
        ps1[t] = xredseg(ps1[t]); pq1[t] = xredseg(pq1[t]);
        psd[t] = xredseg(psd[t]); pqd[t] = xredseg(pqd[t]);
    }
    if (lane < 16) {
#pragma unroll
        for (int t = 0; t < 4; t++) {
            atomicAdd(&stats[0 * 64 + t * 16 + lane], ps1[t]);
            atomicAdd(&stats[1 * 64 + t * 16 + lane], pq1[t]);
            atomicAdd(&stats[2 * 64 + t * 16 + lane], psd[t]);
            atomicAdd(&stats[3 * 64 + t * 16 + lane], pqd[t]);
        }
    }
}

// ---------------- conv2: LDS-staged gather-MFMA on RAW y1, BN1+ReLU fused ----------------
// y1 rows staged raw (pre-BN); BN1+ReLU applied in registers after ds_read.
// Numerically identical to the old separate k_bnrelu pass (same two bf16
// quantization points), saves its 256 MB round-trip + a launch. Each lane's
// channel sets are fixed by seg, so scale/shift live in 16 registers.
#define TILE_B (16 * KK * 128)     // 18432 B per buffer

__global__ __launch_bounds__(128, 2) void k_conv2(
    const __bf16* __restrict__ h1b, const int* __restrict__ nbr,
    const __bf16* __restrict__ W2T, const float* __restrict__ g1,
    const float* __restrict__ b1,
    float* __restrict__ y2, float* __restrict__ stats) {
    __shared__ __align__(16) char smem[2][TILE_B];   // 36864 B -> 4 blocks/CU

    const int lane = threadIdx.x & 63;
    const int w    = threadIdx.x >> 6;      // 0..1 = co-half (thalf)
    const int r    = lane & 15;
    const int seg  = lane >> 4;

    bf16x8 w2[KK][2][2];                    // [k][t2][s]
#pragma unroll
    for (int k = 0; k < KK; k++)
#pragma unroll
        for (int t2 = 0; t2 < 2; t2++)
#pragma unroll
            for (int s = 0; s < 2; s++) {
                int co = w * 32 + t2 * 16 + r;
                int ci = s * 32 + seg * 8;
                w2[k][t2][s] = *(const bf16x8*)(W2T + ((size_t)(k * CO + co)) * CO + ci);
            }

    // BN1 scale/shift for this lane's fixed channel sets:
    // a0 covers ci = seg*8+j, a1 covers ci = 32+seg*8+j
    float scA[8], shA[8], scB[8], shB[8];
#pragma unroll
    for (int j = 0; j < 8; j++) {
        int cA = seg * 8 + j;
        float muA = stats[cA] * (1.0f / NV);
        float vaA = stats[64 + cA] * (1.0f / NV) - muA * muA;
        float sA  = g1[cA] * rsqrtf(vaA + EPSV);
        scA[j] = sA; shA[j] = b1[cA] - muA * sA;
        int cB = 32 + seg * 8 + j;
        float muB = stats[cB] * (1.0f / NV);
        float vaB = stats[64 + cB] * (1.0f / NV) - muB * muB;
        float sB  = g1[cB] * rsqrtf(vaB + EPSV);
        scB[j] = sB; shB[j] = b1[cB] - muB * sB;
    }

    float ps[2] = {0.f, 0.f}, pq[2] = {0.f, 0.f};
    const f32x4 z = {0.f, 0.f, 0.f, 0.f};
    const int sw = r & 7;

    auto stage = [&](char* buf, int it) {
        const int* nb = nbr + (size_t)it * (16 * KK);
#pragma unroll
        for (int s = 0; s < 9; s++) {
            int c = w * 576 + s * 64 + lane;
            int ruleIdx = c >> 3;
            int i = (ruleIdx * 57) >> 9;          // floor(ruleIdx/9), ruleIdx<512
            int p = (c & 7) ^ (i & 7);
            int idx = nb[ruleIdx];
            const __bf16* src = h1b + (size_t)idx * CO + p * 8;
            __builtin_amdgcn_global_load_lds(
                (const __attribute__((address_space(1))) void*)src,
                (__attribute__((address_space(3))) void*)(buf + w * 9216 + s * 1024),
                16, 0, 0);
        }
    };

    int it = blockIdx.x;
    int cur = 0;
    if (it < NG) stage(smem[0], it);
    __syncthreads();                         // drains vmcnt(0) before barrier

    for (; it < NG; it += gridDim.x) {
        int nxt = it + gridDim.x;
        if (nxt < NG) stage(smem[cur ^ 1], nxt);   // prefetch overlaps compute

        // ---- compute on staged tile ----
        const __bf16* base = (const __bf16*)smem[cur];
        f32x4 acc[2] = {z, z};
#pragma unroll
        for (int k = 0; k < KK; k++) {
            const __bf16* rp = base + (size_t)(r * KK + k) * 64;
            bf16x8 a0r = *(const bf16x8*)(rp + ((seg ^ sw) * 8));
            bf16x8 a1r = *(const bf16x8*)(rp + (((4 + seg) ^ sw) * 8));
            bf16x8 a0, a1;
#pragma unroll
            for (int j = 0; j < 8; j++) {
                a0[j] = (__bf16)fmaxf((float)a0r[j] * scA[j] + shA[j], 0.f);
                a1[j] = (__bf16)fmaxf((float)a1r[j] * scB[j] + shB[j], 0.f);
            }
            acc[0] = mfma16(a0, w2[k][0][0], acc[0]);
            acc[0] = mfma16(a1, w2[k][0][1], acc[0]);
            acc[1] = mfma16(a0, w2[k][1][0], acc[1]);
            acc[1] = mfma16(a1, w2[k][1][1], acc[1]);
        }

        const int vb = it * 16;
#pragma unroll
        for (int t2 = 0; t2 < 2; t2++) {
#pragma unroll
            for (int rr = 0; rr < 4; rr++) {
                float val = acc[t2][rr];
                int row = vb + seg * 4 + rr;
                int c = w * 32 + t2 * 16 + r;
                // non-temporal: y2 write stream must not evict h1b from L3
                __builtin_nontemporal_store(val, &y2[(size_t)row * CO + c]);
                ps[t2] += val; pq[t2] += val * val;
            }
        }

        __syncthreads();                     // drains staging vmcnt + barrier
        cur ^= 1;
    }

#pragma unroll
    for (int t2 = 0; t2 < 2; t2++) { ps[t2] = xredseg(ps[t2]); pq[t2] = xredseg(pq[t2]); }
    if (lane < 16) {
#pragma unroll
        for (int t2 = 0; t2 < 2; t2++) {
            atomicAdd(&stats[4 * 64 + w * 32 + t2 * 16 + lane], ps[t2]);
            atomicAdd(&stats[5 * 64 + w * 32 + t2 * 16 + lane], pq[t2]);
        }
    }
}

// ---------------- final: out = relu(BN2(y2) + BNd(xb@WdT)), in place on d_out ----------------
__global__ __launch_bounds__(256, 2) void k_final(
    const __bf16* __restrict__ xb, const __bf16* __restrict__ WdT,
    float* __restrict__ out, const float* __restrict__ stats,
    const float* __restrict__ g2, const float* __restrict__ b2,
    const float* __restrict__ gd, const float* __restrict__ bd) {
    __shared__ float s2[CO], sh2[CO], sdv[CO], shd[CO];
    int t = threadIdx.x;
    if (t < CO) {
        float mu2  = stats[4 * 64 + t] * (1.0f / NV);
        float var2 = stats[5 * 64 + t] * (1.0f / NV) - mu2 * mu2;
        float s = g2[t] * rsqrtf(var2 + EPSV);
        s2[t] = s; sh2[t] = b2[t] - mu2 * s;
        float mud  = stats[2 * 64 + t] * (1.0f / NV);
        float vard = stats[3 * 64 + t] * (1.0f / NV) - mud * mud;
        float sd = gd[t] * rsqrtf(vard + EPSV);
        sdv[t] = sd; shd[t] = bd[t] - mud * sd;
    }
    __syncthreads();

    const int lane = threadIdx.x & 63;
    const int w    = threadIdx.x >> 6;
    const int r    = lane & 15;
    const int seg  = lane >> 4;

    bf16x8 wd[4];
#pragma unroll
    for (int t4 = 0; t4 < 4; t4++)
        wd[t4] = *(const bf16x8*)(WdT + (size_t)(t4 * 16 + r) * CI + seg * 8);

    const int slot = blockIdx.x * 4 + w;
    const int nslots = gridDim.x * 4;
    const f32x4 z = {0.f, 0.f, 0.f, 0.f};

    for (int gid = slot; gid < NG; gid += nslots) {
        const int vb = gid * 16;
        const int v  = vb + r;
        bf16x8 ad = *(const bf16x8*)(xb + (size_t)v * CI + seg * 8);
        f32x4 accd[4] = {z, z, z, z};
#pragma unroll
        for (int t4 = 0; t4 < 4; t4++) accd[t4] = mfma16(ad, wd[t4], accd[t4]);
#pragma unroll
        for (int t4 = 0; t4 < 4; t4++) {
#pragma unroll
            for (int rr = 0; rr < 4; rr++) {
                int row = vb + seg * 4 + rr;
                int c = t4 * 16 + r;
                size_t o = (size_t)row * CO + c;
                float y2v = out[o];
                float res = s2[c] * y2v + sh2[c] + sdv[c] * accd[t4][rr] + shd[c];
                out[o] = fmaxf(res, 0.f);
            }
        }
    }
}

extern "C" void kernel_launch(void* const* d_in, const int* in_sizes, int n_in,
                              void* d_out, int out_size, void* d_ws, size_t ws_size,
                              hipStream_t stream) {
    const float* x  = (const float*)d_in[0];
    const float* W1 = (const float*)d_in[1];
    const float* g1 = (const float*)d_in[2];
    const float* b1 = (const float*)d_in[3];
    const float* W2 = (const float*)d_in[4];
    const float* g2 = (const float*)d_in[5];
    const float* b2 = (const float*)d_in[6];
    const float* Wd = (const float*)d_in[7];
    const float* gd = (const float*)d_in[8];
    const float* bd = (const float*)d_in[9];
    const int*  nbr = (const int*)d_in[10];

    char* ws = (char*)d_ws;
    __bf16* xb  = (__bf16*)ws;                              // 64,000,000 B
    __bf16* y1b = (__bf16*)(ws + 64000000);                 // 128,000,000 B
    __bf16* W1T = (__bf16*)(ws + 192000000);                // 36,864 B
    __bf16* W2T = W1T + KK * CO * CI;                       // 73,728 B
    __bf16* WdT = W2T + KK * CO * CO;                       // 4,096 B
    float* stats = (float*)(ws + 192000000 + 2 * (KK*CO*CI + KK*CO*CO + CO*CI));

    hipMemsetAsync(stats, 0, 6 * 64 * sizeof(float), stream);

    int nprep = KK*CO*CI + KK*CO*CO + CO*CI;                // 57344
    k_prep_w<<<(nprep + 255) / 256, 256, 0, stream>>>(W1, W2, Wd, W1T, W2T, WdT);
    k_prep_x<<<(NV * CI / 8) / 256, 256, 0, stream>>>(x, xb);   // 15625 blocks
    k_conv1<<<768, 256, 0, stream>>>(xb, nbr, W1T, WdT, y1b, stats);
    k_conv2<<<1024, 128, 0, stream>>>(y1b, nbr, W2T, g1, b1, (float*)d_out, stats);
    k_final<<<1024, 256, 0, stream>>>(xb, WdT, (float*)d_out, stats, g2, b2, gd, bd);
}